// Round 1
// baseline (360.877 us; speedup 1.0000x reference)
//
#include <hip/hip_runtime.h>
#include <hip/hip_bf16.h>
#include <stdint.h>

#define NUM_EMB 4096
#define EMB_DIM 256
#define NVEC 65536                     // 64*32*32
#define OUT0_SIZE (NVEC * EMB_DIM)     // z_q_ste elements; loss scalar follows
#define MTILE 128                      // z rows per block
#define NTILE 64                       // codebook entries per LDS tile
#define LROW 544                       // bytes per entry row in LDS (512 + 32 pad -> 2-way only)

typedef __bf16 bf16x8 __attribute__((ext_vector_type(8)));
typedef float floatx4 __attribute__((ext_vector_type(4)));

static __device__ __forceinline__ unsigned int f2bf(float f) {
  unsigned int u = __float_as_uint(f);
  return (u + 0x7fffu + ((u >> 16) & 1u)) >> 16;  // RNE fp32->bf16
}

static __device__ __forceinline__ uint4 pack_bf8(float4 a, float4 b) {
  uint4 r;
  r.x = f2bf(a.x) | (f2bf(a.y) << 16);
  r.y = f2bf(a.z) | (f2bf(a.w) << 16);
  r.z = f2bf(b.x) | (f2bf(b.y) << 16);
  r.w = f2bf(b.z) | (f2bf(b.w) << 16);
  return r;
}

// Prep: codebook fp32 -> bf16 (ws), ||e||^2 (ws), zero loss slot.
__global__ void __launch_bounds__(256) vq_prep(const float* __restrict__ cbf,
                                               unsigned short* __restrict__ cbb,
                                               float* __restrict__ enorm,
                                               float* __restrict__ out) {
  int w = threadIdx.x >> 6;
  int lane = threadIdx.x & 63;
  int row = blockIdx.x * 4 + w;
  float4 v = ((const float4*)(cbf + (size_t)row * EMB_DIM))[lane];
  float ss = v.x * v.x + v.y * v.y + v.z * v.z + v.w * v.w;
  ushort4 b;
  b.x = (unsigned short)f2bf(v.x);
  b.y = (unsigned short)f2bf(v.y);
  b.z = (unsigned short)f2bf(v.z);
  b.w = (unsigned short)f2bf(v.w);
  ((ushort4*)(cbb + (size_t)row * EMB_DIM))[lane] = b;
#pragma unroll
  for (int m = 1; m < 64; m <<= 1) ss += __shfl_xor(ss, m, 64);
  if (lane == 0) enorm[row] = ss;
  if (blockIdx.x == 0 && threadIdx.x == 0) out[OUT0_SIZE] = 0.0f;
}

// Main: fused distance-GEMM (bf16 MFMA) + argmin + gather + STE output + loss.
__global__ void __launch_bounds__(256, 2) vq_main(const float* __restrict__ z,
                                                  const float* __restrict__ cbf,
                                                  const unsigned short* __restrict__ cbb,
                                                  const float* __restrict__ enorm,
                                                  float* __restrict__ out) {
  __shared__ unsigned char lds[NTILE * LROW];
  __shared__ float lds_en[NTILE];
  __shared__ float wsum[4];

  const int t = threadIdx.x;
  const int w = t >> 6;        // wave 0..3, owns 32 z rows
  const int lane = t & 63;
  const int q = lane >> 4;     // quad within wave
  const int i = lane & 15;
  const int blk = blockIdx.x;
  const int row_base = blk * MTILE + w * 32;

  // A-frags: wave's 32 z rows (2 groups of 16) x D=256 as bf16, resident in regs.
  // A layout for 16x16x32: m = lane&15, k = quad*8 + j (8 contiguous bf16).
  uint4 afrag[2][8];
#pragma unroll
  for (int g = 0; g < 2; ++g) {
#pragma unroll
    for (int ks = 0; ks < 8; ++ks) {
      const float4* p =
          (const float4*)(z + (size_t)(row_base + g * 16 + i) * EMB_DIM + ks * 32 + q * 8);
      afrag[g][ks] = pack_bf8(p[0], p[1]);
    }
  }

  // Running argmin. Slots: [g*4+r] -> z row = row_base + g*16 + q*4 + r (C layout).
  float minv[8];
  int mini[8];
#pragma unroll
  for (int s = 0; s < 8; ++s) { minv[s] = 3.402823466e+38f; mini[s] = 0; }

  for (int c0 = 0; c0 < NUM_EMB; c0 += NTILE) {
    __syncthreads();
    // Stage 64 entries x 256 bf16 -> LDS (coalesced global, padded rows).
#pragma unroll
    for (int j = 0; j < 8; ++j) {
      int id = t + 256 * j;      // 2048 16B-chunks
      int e = id >> 5, kc = id & 31;
      uint4 v = *(const uint4*)(cbb + (size_t)(c0 + e) * EMB_DIM + kc * 8);
      *(uint4*)(lds + e * LROW + kc * 16) = v;
    }
    if (t < NTILE) lds_en[t] = enorm[c0 + t];
    __syncthreads();

#pragma unroll
    for (int ct = 0; ct < 4; ++ct) {   // 16-entry column tiles
      floatx4 acc0 = {0.f, 0.f, 0.f, 0.f};
      floatx4 acc1 = {0.f, 0.f, 0.f, 0.f};
#pragma unroll
      for (int ks = 0; ks < 8; ++ks) { // D = 8 x 32
        bf16x8 bf = __builtin_bit_cast(
            bf16x8, *(const uint4*)(lds + (ct * 16 + i) * LROW + (ks * 4 + q) * 16));
        acc0 = __builtin_amdgcn_mfma_f32_16x16x32_bf16(
            __builtin_bit_cast(bf16x8, afrag[0][ks]), bf, acc0, 0, 0, 0);
        acc1 = __builtin_amdgcn_mfma_f32_16x16x32_bf16(
            __builtin_bit_cast(bf16x8, afrag[1][ks]), bf, acc1, 0, 0, 0);
      }
      // d = -2*(z.e) + ||e||^2  (||z||^2 is row-constant, irrelevant for argmin)
      int col = c0 + ct * 16 + i;
      float en = lds_en[ct * 16 + i];
#pragma unroll
      for (int r = 0; r < 4; ++r) {
        float d0 = fmaf(-2.f, acc0[r], en);
        if (d0 < minv[r]) { minv[r] = d0; mini[r] = col; }
        float d1 = fmaf(-2.f, acc1[r], en);
        if (d1 < minv[4 + r]) { minv[4 + r] = d1; mini[4 + r] = col; }
      }
    }
  }

  // Min over the 16 column-lanes (xor 1,2,4,8 stays within quad-group).
  // Tie rule: smaller index (np.argmin semantics).
#pragma unroll
  for (int s = 0; s < 8; ++s) {
    float v = minv[s];
    int ix = mini[s];
#pragma unroll
    for (int m = 1; m <= 8; m <<= 1) {
      float ov = __shfl_xor(v, m, 64);
      int oi = __shfl_xor(ix, m, 64);
      if (ov < v || (ov == v && oi < ix)) { v = ov; ix = oi; }
    }
    minv[s] = v;
    mini[s] = ix;
  }

  __syncthreads();               // all waves done reading e-tile LDS
  int* idx_lds = (int*)lds;      // reuse e-tile region for 128 indices
  if (i == 0) {
#pragma unroll
    for (int g = 0; g < 2; ++g)
#pragma unroll
      for (int r = 0; r < 4; ++r)
        idx_lds[w * 32 + g * 16 + q * 4 + r] = mini[g * 4 + r];
  }
  __syncthreads();

  // Gather z_q, write z + (z_q - z) (STE forward), accumulate loss.
  float lacc = 0.f;
#pragma unroll 4
  for (int j = 0; j < 32; ++j) {
    int id4 = j * 256 + t;       // float4 index within 128x256 tile
    int r = id4 >> 6, c4 = id4 & 63;
    int grow = blk * MTILE + r;
    float4 zv = ((const float4*)(z + (size_t)grow * EMB_DIM))[c4];
    int k = idx_lds[r];
    float4 ev = ((const float4*)(cbf + (size_t)k * EMB_DIM))[c4];
    float4 d;
    d.x = ev.x - zv.x; d.y = ev.y - zv.y; d.z = ev.z - zv.z; d.w = ev.w - zv.w;
    float4 o;
    o.x = zv.x + d.x; o.y = zv.y + d.y; o.z = zv.z + d.z; o.w = zv.w + d.w;
    ((float4*)(out + (size_t)grow * EMB_DIM))[c4] = o;
    lacc += d.x * d.x + d.y * d.y + d.z * d.z + d.w * d.w;
  }
#pragma unroll
  for (int m = 1; m < 64; m <<= 1) lacc += __shfl_xor(lacc, m, 64);
  if (lane == 0) wsum[w] = lacc;
  __syncthreads();
  if (t == 0) {
    float s = (wsum[0] + wsum[1]) + (wsum[2] + wsum[3]);
    // loss = mean((zq-z)^2) + 0.25*mean((zq-z)^2) = 1.25 * sum / N
    atomicAdd(out + OUT0_SIZE, s * (1.25f / (float)OUT0_SIZE));
  }
}

extern "C" void kernel_launch(void* const* d_in, const int* in_sizes, int n_in,
                              void* d_out, int out_size, void* d_ws, size_t ws_size,
                              hipStream_t stream) {
  const float* z = (const float*)d_in[0];
  const float* cbf = (const float*)d_in[1];
  unsigned short* cbb = (unsigned short*)d_ws;                       // 2 MB bf16 codebook
  float* enorm = (float*)((char*)d_ws + (size_t)NUM_EMB * EMB_DIM * 2);  // +16 KB
  float* out = (float*)d_out;
  vq_prep<<<NUM_EMB / 4, 256, 0, stream>>>(cbf, cbb, enorm, out);
  vq_main<<<NVEC / MTILE, 256, 0, stream>>>(z, cbf, cbb, enorm, out);
}

// Round 2
// 260.517 us; speedup vs baseline: 1.3852x; 1.3852x over previous
//
#include <hip/hip_runtime.h>
#include <hip/hip_bf16.h>
#include <stdint.h>

#define NUM_EMB 4096
#define EMB_DIM 256
#define NVEC 65536                     // 64*32*32
#define OUT0_SIZE (NVEC * EMB_DIM)     // z_q_ste elements; loss scalar follows
#define MTILE 128                      // z rows per block
#define NTILE 64                       // codebook entries per LDS tile
#define LROW 528                       // 512 + 16 pad: 132 dwords, 4e mod-128 spread -> conflict-free b128
#define DCONST 0.0625f                 // positivity shift for packed distance

typedef __bf16 bf16x8 __attribute__((ext_vector_type(8)));
typedef float floatx16 __attribute__((ext_vector_type(16)));

static __device__ __forceinline__ unsigned int f2bf(float f) {
  unsigned int u = __float_as_uint(f);
  return (u + 0x7fffu + ((u >> 16) & 1u)) >> 16;  // RNE fp32->bf16
}

static __device__ __forceinline__ uint4 pack_bf8(float4 a, float4 b) {
  uint4 r;
  r.x = f2bf(a.x) | (f2bf(a.y) << 16);
  r.y = f2bf(a.z) | (f2bf(a.w) << 16);
  r.z = f2bf(b.x) | (f2bf(b.y) << 16);
  r.w = f2bf(b.z) | (f2bf(b.w) << 16);
  return r;
}

// Prep: codebook fp32 -> bf16 (ws), ||e||^2 + DCONST (ws), zero loss slot.
__global__ void __launch_bounds__(256) vq_prep(const float* __restrict__ cbf,
                                               unsigned short* __restrict__ cbb,
                                               float* __restrict__ enorm,
                                               float* __restrict__ out) {
  int w = threadIdx.x >> 6;
  int lane = threadIdx.x & 63;
  int row = blockIdx.x * 4 + w;
  float4 v = ((const float4*)(cbf + (size_t)row * EMB_DIM))[lane];
  float ss = v.x * v.x + v.y * v.y + v.z * v.z + v.w * v.w;
  ushort4 b;
  b.x = (unsigned short)f2bf(v.x);
  b.y = (unsigned short)f2bf(v.y);
  b.z = (unsigned short)f2bf(v.z);
  b.w = (unsigned short)f2bf(v.w);
  ((ushort4*)(cbb + (size_t)row * EMB_DIM))[lane] = b;
#pragma unroll
  for (int m = 1; m < 64; m <<= 1) ss += __shfl_xor(ss, m, 64);
  if (lane == 0) enorm[row] = ss + DCONST;
  if (blockIdx.x == 0 && threadIdx.x == 0) out[OUT0_SIZE] = 0.0f;
}

// Main: distance-GEMM (32x32x16 bf16 MFMA, 2 row-groups/wave, wave-pairs split
// cols) + packed argmin + loss-from-distance + gather + output.
__global__ void __launch_bounds__(256, 2) vq_main(const float* __restrict__ z,
                                                  const float* __restrict__ cbf,
                                                  const unsigned short* __restrict__ cbb,
                                                  const float* __restrict__ enorm,
                                                  float* __restrict__ out) {
  __shared__ unsigned char stage[NTILE * LROW];
  __shared__ float lds_en[NTILE];
  __shared__ unsigned int minlds[2][MTILE];
  __shared__ float znorm[MTILE];
  __shared__ int idx_lds[MTILE];
  __shared__ float wsum[4];

  const int t = threadIdx.x;
  const int w = t >> 6;
  const int lane = t & 63;
  const int h = lane >> 5;     // half-wave
  const int eL = lane & 31;
  const int rg = w & 1;        // row group: rows rg*64..+63 of the block tile
  const int cg = w >> 1;       // col group: cols cg*32..+31 of each 64-entry tile
  const int blk = blockIdx.x;
  const int row_base = blk * MTILE + rg * 64;

  // ---- A-phase: 64 z rows (2 groups of 32) x D=256 as bf16 into registers.
  // A layout for 32x32x16: m = lane&31, k = (lane>>5)*8 + j, per 16-k step.
  // Also accumulate per-row ||z||^2 (fp32) into LDS.
  uint4 afrag[2][16];
  float zn[2] = {0.f, 0.f};
#pragma unroll
  for (int g = 0; g < 2; ++g) {
    const float* rp = z + (size_t)(row_base + g * 32 + eL) * EMB_DIM + h * 8;
#pragma unroll
    for (int ks = 0; ks < 16; ++ks) {
      float4 a0 = *(const float4*)(rp + ks * 16);
      float4 a1 = *(const float4*)(rp + ks * 16 + 4);
      zn[g] += a0.x * a0.x + a0.y * a0.y + a0.z * a0.z + a0.w * a0.w
             + a1.x * a1.x + a1.y * a1.y + a1.z * a1.z + a1.w * a1.w;
      afrag[g][ks] = pack_bf8(a0, a1);
    }
    zn[g] += __shfl_xor(zn[g], 32, 64);
  }
  if (w < 2 && h == 0) {
    znorm[rg * 64 + eL] = zn[0];
    znorm[rg * 64 + 32 + eL] = zn[1];
  }

  // Running packed argmin: top-20 bits of positive distance | 12-bit col.
  unsigned int pmin[32];
#pragma unroll
  for (int s = 0; s < 32; ++s) pmin[s] = 0xFFFFFFFFu;

  for (int c0 = 0; c0 < NUM_EMB; c0 += NTILE) {
    __syncthreads();
    // Stage 64 entries x 256 bf16 -> LDS (coalesced, padded rows).
#pragma unroll
    for (int j = 0; j < 8; ++j) {
      int id = t + 256 * j;    // 2048 16B chunks
      int e = id >> 5, kc = id & 31;
      uint4 v = *(const uint4*)(cbb + (size_t)(c0 + e) * EMB_DIM + kc * 8);
      *(uint4*)(stage + e * LROW + kc * 16) = v;
    }
    if (t < NTILE) lds_en[t] = enorm[c0 + t];
    __syncthreads();

    // Wave handles its 32-col half: 16 k-steps, B-frag reused by 2 row groups.
    floatx16 acc0, acc1;
#pragma unroll
    for (int r = 0; r < 16; ++r) { acc0[r] = 0.f; acc1[r] = 0.f; }
    const unsigned char* bp = stage + (cg * 32 + eL) * LROW + h * 16;
#pragma unroll
    for (int ks = 0; ks < 16; ++ks) {
      bf16x8 b = __builtin_bit_cast(bf16x8, *(const uint4*)(bp + ks * 32));
      acc0 = __builtin_amdgcn_mfma_f32_32x32x16_bf16(
          __builtin_bit_cast(bf16x8, afrag[0][ks]), b, acc0, 0, 0, 0);
      acc1 = __builtin_amdgcn_mfma_f32_32x32x16_bf16(
          __builtin_bit_cast(bf16x8, afrag[1][ks]), b, acc1, 0, 0, 0);
    }

    // d = -2*(z.e) + (||e||^2 + C) > 0; pack top-20 bits with col index.
    float enC = lds_en[cg * 32 + eL];
    unsigned int colb = (unsigned int)(c0 + cg * 32 + eL);
#pragma unroll
    for (int reg = 0; reg < 16; ++reg) {
      float d0 = fmaf(-2.f, acc0[reg], enC);
      unsigned int p0 = (__float_as_uint(d0) & 0xFFFFF000u) | colb;
      if (p0 < pmin[reg]) pmin[reg] = p0;
      float d1 = fmaf(-2.f, acc1[reg], enC);
      unsigned int p1 = (__float_as_uint(d1) & 0xFFFFF000u) | colb;
      if (p1 < pmin[16 + reg]) pmin[16 + reg] = p1;
    }
  }

  // Reduce over the 32 col-lanes (xor 1..16 stays within half-wave; halves
  // cover disjoint row sets). Packed u32 min = (distance, index) lexicographic
  // -> smallest-index tiebreak like np.argmin.
#pragma unroll
  for (int s = 0; s < 32; ++s) {
    unsigned int v = pmin[s];
#pragma unroll
    for (int m = 1; m <= 16; m <<= 1) {
      unsigned int o = __shfl_xor(v, m, 64);
      if (o < v) v = o;
    }
    pmin[s] = v;
  }
  // C/D layout 32x32: row = (reg&3) + 8*(reg>>2) + 4*(lane>>5), col = lane&31.
  if (eL == 0) {
#pragma unroll
    for (int s = 0; s < 32; ++s) {
      int g = s >> 4, reg = s & 15;
      int rowl = rg * 64 + g * 32 + (reg & 3) + 8 * (reg >> 2) + 4 * h;
      minlds[cg][rowl] = pmin[s];
    }
  }
  __syncthreads();

  // Combine col-halves; recover idx + distance; loss = sum(||z||^2 + d - C).
  float rl = 0.f;
  if (t < MTILE) {
    unsigned int m0 = minlds[0][t], m1 = minlds[1][t];
    unsigned int m = m1 < m0 ? m1 : m0;
    idx_lds[t] = (int)(m & 0xFFFu);
    rl = znorm[t] + __uint_as_float(m & 0xFFFFF000u) - DCONST;
  }
#pragma unroll
  for (int m = 1; m < 64; m <<= 1) rl += __shfl_xor(rl, m, 64);
  if (lane == 0) wsum[w] = rl;
  __syncthreads();
  if (t == 0) {
    float s = (wsum[0] + wsum[1]) + (wsum[2] + wsum[3]);
    atomicAdd(out + OUT0_SIZE, s * (1.25f / (float)OUT0_SIZE));
  }

  // Gather phase: out = codebook[idx] (== z + (z_q - z) to ~3e-7).
#pragma unroll 4
  for (int j = 0; j < 32; ++j) {
    int id4 = j * 256 + t;     // float4 index within 128x256 tile
    int r = id4 >> 6, c4 = id4 & 63;
    int k = idx_lds[r];
    float4 ev = ((const float4*)(cbf + (size_t)k * EMB_DIM))[c4];
    ((float4*)(out + (size_t)(blk * MTILE + r) * EMB_DIM))[c4] = ev;
  }
}

extern "C" void kernel_launch(void* const* d_in, const int* in_sizes, int n_in,
                              void* d_out, int out_size, void* d_ws, size_t ws_size,
                              hipStream_t stream) {
  const float* z = (const float*)d_in[0];
  const float* cbf = (const float*)d_in[1];
  unsigned short* cbb = (unsigned short*)d_ws;                           // 2 MB bf16 codebook
  float* enorm = (float*)((char*)d_ws + (size_t)NUM_EMB * EMB_DIM * 2);  // +16 KB
  float* out = (float*)d_out;
  vq_prep<<<NUM_EMB / 4, 256, 0, stream>>>(cbf, cbb, enorm, out);
  vq_main<<<NVEC / MTILE, 256, 0, stream>>>(z, cbf, cbb, enorm, out);
}